// Round 1
// baseline (162.819 us; speedup 1.0000x reference)
//
#include <hip/hip_runtime.h>

static constexpr int DIM  = 192;
static constexpr int NVOX = 2 * DIM * DIM * DIM;   // 14,155,776 voxels (b=2, c=1)
static constexpr int N4   = NVOX / 4;              // 3,538,944
static constexpr int TSIZE = NVOX;                 // floats in "transformed" output

// ---------------- Kernel 1: eight reductions over x and y ----------------
// ws[0..3] = sum(x), sum(x*gx), sum(x*gy), sum(x*gz)
// ws[4..7] = same for y
__global__ __launch_bounds__(256) void com_reduce(const float* __restrict__ x,
                                                  const float* __restrict__ y,
                                                  double* __restrict__ ws) {
    const float step = 2.0f / 191.0f;
    double a0 = 0, a1 = 0, a2 = 0, a3 = 0;
    double b0 = 0, b1 = 0, b2 = 0, b3 = 0;

    for (int t = blockIdx.x * blockDim.x + threadIdx.x; t < N4;
         t += gridDim.x * blockDim.x) {
        int idx = t * 4;
        int k = idx % DIM;          // fastest axis (d) -> gx
        int r = idx / DIM;
        int j = r % DIM;            // w axis -> gy
        int i = (r / DIM) % DIM;    // h axis -> gz (batch index irrelevant here)

        float4 xv = reinterpret_cast<const float4*>(x)[t];
        float4 yv = reinterpret_cast<const float4*>(y)[t];

        float gj = fmaf((float)j, step, -1.0f);
        float gi = fmaf((float)i, step, -1.0f);
        float g0 = fmaf((float)(k + 0), step, -1.0f);
        float g1 = fmaf((float)(k + 1), step, -1.0f);
        float g2 = fmaf((float)(k + 2), step, -1.0f);
        float g3 = fmaf((float)(k + 3), step, -1.0f);

        float xs  = (xv.x + xv.y) + (xv.z + xv.w);
        float ys  = (yv.x + yv.y) + (yv.z + yv.w);
        float xgx = xv.x * g0 + xv.y * g1 + xv.z * g2 + xv.w * g3;
        float ygx = yv.x * g0 + yv.y * g1 + yv.z * g2 + yv.w * g3;

        a0 += (double)xs;  a1 += (double)xgx;
        a2 += (double)(xs * gj); a3 += (double)(xs * gi);
        b0 += (double)ys;  b1 += (double)ygx;
        b2 += (double)(ys * gj); b3 += (double)(ys * gi);
    }

    double v[8] = {a0, a1, a2, a3, b0, b1, b2, b3};
#pragma unroll
    for (int q = 0; q < 8; ++q) {
#pragma unroll
        for (int off = 32; off > 0; off >>= 1)
            v[q] += __shfl_down(v[q], off, 64);
    }

    __shared__ double sm[4][8];
    int lane = threadIdx.x & 63;
    int wave = threadIdx.x >> 6;
    if (lane == 0) {
#pragma unroll
        for (int q = 0; q < 8; ++q) sm[wave][q] = v[q];
    }
    __syncthreads();
    if (threadIdx.x < 8) {
        double s = sm[0][threadIdx.x] + sm[1][threadIdx.x] +
                   sm[2][threadIdx.x] + sm[3][threadIdx.x];
        atomicAdd(&ws[threadIdx.x], s);
    }
}

// ---------------- Kernel 2: constant-shift trilinear sample + grid write ----------------
__global__ __launch_bounds__(256) void com_apply(const float* __restrict__ x,
                                                 float* __restrict__ out,
                                                 const double* __restrict__ ws) {
    int t = blockIdx.x * blockDim.x + threadIdx.x;
    if (t >= N4) return;

    // uniform scalars (compiler keeps these in SGPRs; L2-broadcast loads)
    double xs  = ws[0], xgx = ws[1], xgy = ws[2], xgz = ws[3];
    double ysm = ws[4], ygx = ws[5], ygy = ws[6], ygz = ws[7];
    double tx = xgx / xs - ygx / ysm;
    double ty = xgy / xs - ygy / ysm;
    double tz = xgz / xs - ygz / ysm;
    // ix = k + tx*0.5*(W-1), etc.  (pure translation since grid = linspace + t)
    double sx = tx * 95.5, sy = ty * 95.5, sz = tz * 95.5;
    double fsx = floor(sx), fsy = floor(sy), fsz = floor(sz);
    float fx = (float)(sx - fsx), fy = (float)(sy - fsy), fz = (float)(sz - fsz);
    int iox = (int)fsx, ioy = (int)fsy, ioz = (int)fsz;
    float txf = (float)tx, tyf = (float)ty, tzf = (float)tz;

    int idx = t * 4;
    int k  = idx % DIM;
    int r  = idx / DIM;
    int j  = r % DIM;
    int r2 = r / DIM;
    int i  = r2 % DIM;
    int b  = r2 / DIM;

    // per-axis indices/weights; validity (zeros padding) folded into weights
    int z0 = i + ioz, z1 = z0 + 1;
    float wz0 = (z0 >= 0 && z0 < DIM) ? (1.0f - fz) : 0.0f;
    float wz1 = (z1 >= 0 && z1 < DIM) ? fz : 0.0f;
    int zc0 = min(max(z0, 0), DIM - 1), zc1 = min(max(z1, 0), DIM - 1);

    int y0 = j + ioy, y1 = y0 + 1;
    float wy0 = (y0 >= 0 && y0 < DIM) ? (1.0f - fy) : 0.0f;
    float wy1 = (y1 >= 0 && y1 < DIM) ? fy : 0.0f;
    int yc0 = min(max(y0, 0), DIM - 1), yc1 = min(max(y1, 0), DIM - 1);

    const float* xb  = x + (size_t)b * DIM * DIM * DIM;
    const float* r00 = xb + (zc0 * DIM + yc0) * DIM;
    const float* r01 = xb + (zc0 * DIM + yc1) * DIM;
    const float* r10 = xb + (zc1 * DIM + yc0) * DIM;
    const float* r11 = xb + (zc1 * DIM + yc1) * DIM;
    float w00 = wz0 * wy0, w01 = wz0 * wy1, w10 = wz1 * wy0, w11 = wz1 * wy1;

    float res[4];
#pragma unroll
    for (int m = 0; m < 4; ++m) {
        int c0 = k + m + iox, c1 = c0 + 1;
        float wx0 = (c0 >= 0 && c0 < DIM) ? (1.0f - fx) : 0.0f;
        float wx1 = (c1 >= 0 && c1 < DIM) ? fx : 0.0f;
        int cc0 = min(max(c0, 0), DIM - 1), cc1 = min(max(c1, 0), DIM - 1);
        float v00 = wx0 * r00[cc0] + wx1 * r00[cc1];
        float v01 = wx0 * r01[cc0] + wx1 * r01[cc1];
        float v10 = wx0 * r10[cc0] + wx1 * r10[cc1];
        float v11 = wx0 * r11[cc0] + wx1 * r11[cc1];
        res[m] = w00 * v00 + w01 * v01 + w10 * v10 + w11 * v11;
    }
    reinterpret_cast<float4*>(out)[t] =
        make_float4(res[0], res[1], res[2], res[3]);

    // grid output: (gx[k]+tx, gy[j]+ty, gz[i]+tz) per voxel, 12 consecutive floats
    const float step = 2.0f / 191.0f;
    float gj = fmaf((float)j, step, -1.0f) + tyf;
    float gi = fmaf((float)i, step, -1.0f) + tzf;
    float g0 = fmaf((float)(k + 0), step, -1.0f) + txf;
    float g1 = fmaf((float)(k + 1), step, -1.0f) + txf;
    float g2 = fmaf((float)(k + 2), step, -1.0f) + txf;
    float g3 = fmaf((float)(k + 3), step, -1.0f) + txf;

    float* g = out + TSIZE + (size_t)idx * 3;
    reinterpret_cast<float4*>(g)[0] = make_float4(g0, gj, gi, g1);
    reinterpret_cast<float4*>(g)[1] = make_float4(gj, gi, g2, gj);
    reinterpret_cast<float4*>(g)[2] = make_float4(gi, g3, gj, gi);
}

extern "C" void kernel_launch(void* const* d_in, const int* in_sizes, int n_in,
                              void* d_out, int out_size, void* d_ws, size_t ws_size,
                              hipStream_t stream) {
    const float* x = (const float*)d_in[0];
    const float* y = (const float*)d_in[1];
    float* out = (float*)d_out;
    double* ws = (double*)d_ws;

    hipMemsetAsync(ws, 0, 8 * sizeof(double), stream);
    com_reduce<<<1024, 256, 0, stream>>>(x, y, ws);
    com_apply<<<N4 / 256, 256, 0, stream>>>(x, out, ws);
}

// Round 2
// 115.274 us; speedup vs baseline: 1.4125x; 1.4125x over previous
//
#include <hip/hip_runtime.h>

static constexpr int DIM   = 192;
static constexpr int NVOX  = 2 * DIM * DIM * DIM;   // 14,155,776
static constexpr int N4    = NVOX / 4;              // 3,538,944
static constexpr int TSIZE = NVOX;

// ---------------- Kernel 1: eight reductions over x and y ----------------
// ws[0..3] = sum(x), sum(x*gx), sum(x*gy), sum(x*gz); ws[4..7] = same for y
__global__ __launch_bounds__(256) void com_reduce(const float* __restrict__ x,
                                                  const float* __restrict__ y,
                                                  double* __restrict__ ws) {
    const float step = 2.0f / 191.0f;
    float a0 = 0, a1 = 0, a2 = 0, a3 = 0;
    float b0 = 0, b1 = 0, b2 = 0, b3 = 0;

    for (int t = blockIdx.x * blockDim.x + threadIdx.x; t < N4;
         t += gridDim.x * blockDim.x) {
        int idx = t * 4;
        int k = idx % DIM;
        int r = idx / DIM;
        int j = r % DIM;
        int i = (r / DIM) % DIM;

        float4 xv = reinterpret_cast<const float4*>(x)[t];
        float4 yv = reinterpret_cast<const float4*>(y)[t];

        float gj = fmaf((float)j, step, -1.0f);
        float gi = fmaf((float)i, step, -1.0f);
        float g0 = fmaf((float)(k + 0), step, -1.0f);
        float g1 = fmaf((float)(k + 1), step, -1.0f);
        float g2 = fmaf((float)(k + 2), step, -1.0f);
        float g3 = fmaf((float)(k + 3), step, -1.0f);

        float xs  = (xv.x + xv.y) + (xv.z + xv.w);
        float ys  = (yv.x + yv.y) + (yv.z + yv.w);
        float xgx = xv.x * g0 + xv.y * g1 + xv.z * g2 + xv.w * g3;
        float ygx = yv.x * g0 + yv.y * g1 + yv.z * g2 + yv.w * g3;

        a0 += xs;  a1 += xgx;  a2 += xs * gj;  a3 += xs * gi;
        b0 += ys;  b1 += ygx;  b2 += ys * gj;  b3 += ys * gi;
    }

    float v[8] = {a0, a1, a2, a3, b0, b1, b2, b3};
#pragma unroll
    for (int q = 0; q < 8; ++q) {
#pragma unroll
        for (int off = 32; off > 0; off >>= 1)
            v[q] += __shfl_down(v[q], off, 64);
    }

    __shared__ float sm[4][8];
    int lane = threadIdx.x & 63;
    int wave = threadIdx.x >> 6;
    if (lane == 0) {
#pragma unroll
        for (int q = 0; q < 8; ++q) sm[wave][q] = v[q];
    }
    __syncthreads();
    if (threadIdx.x < 8) {
        double s = (double)sm[0][threadIdx.x] + (double)sm[1][threadIdx.x] +
                   (double)sm[2][threadIdx.x] + (double)sm[3][threadIdx.x];
        atomicAdd(&ws[threadIdx.x], s);
    }
}

// ---------------- Kernel 1.5: fold reductions into sampling params ----------------
// writes: wp[0..5] = fx, fy, fz, tx, ty, tz (float); ip[0..2] = iox, ioy, ioz (int)
__global__ void com_finalize(double* __restrict__ ws) {
    if (threadIdx.x == 0 && blockIdx.x == 0) {
        double tx = ws[1] / ws[0] - ws[5] / ws[4];
        double ty = ws[2] / ws[0] - ws[6] / ws[4];
        double tz = ws[3] / ws[0] - ws[7] / ws[4];
        double sx = tx * 95.5, sy = ty * 95.5, sz = tz * 95.5;
        double fsx = floor(sx), fsy = floor(sy), fsz = floor(sz);
        float* wp = reinterpret_cast<float*>(ws + 8);
        wp[0] = (float)(sx - fsx);
        wp[1] = (float)(sy - fsy);
        wp[2] = (float)(sz - fsz);
        wp[3] = (float)tx;
        wp[4] = (float)ty;
        wp[5] = (float)tz;
        int* ip = reinterpret_cast<int*>(wp + 6);
        ip[0] = (int)fsx; ip[1] = (int)fsy; ip[2] = (int)fsz;
    }
}

// ---------------- Kernel 2: constant-shift trilinear sample + grid write ----------------
__global__ __launch_bounds__(256) void com_apply(const float* __restrict__ x,
                                                 float* __restrict__ out,
                                                 const double* __restrict__ ws) {
    int t = blockIdx.x * blockDim.x + threadIdx.x;
    if (t >= N4) return;

    const float* wp = reinterpret_cast<const float*>(ws + 8);
    const int*   ip = reinterpret_cast<const int*>(wp + 6);
    float fx = wp[0], fy = wp[1], fz = wp[2];
    float txf = wp[3], tyf = wp[4], tzf = wp[5];
    int iox = ip[0], ioy = ip[1], ioz = ip[2];

    int idx = t * 4;
    int k  = idx % DIM;          // multiple of 4
    int r  = idx / DIM;
    int j  = r % DIM;
    int r2 = r / DIM;
    int i  = r2 % DIM;
    int b  = r2 / DIM;

    int z0 = i + ioz, z1 = z0 + 1;
    float wz0 = (z0 >= 0 && z0 < DIM) ? (1.0f - fz) : 0.0f;
    float wz1 = (z1 >= 0 && z1 < DIM) ? fz : 0.0f;
    int zc0 = min(max(z0, 0), DIM - 1), zc1 = min(max(z1, 0), DIM - 1);

    int y0 = j + ioy, y1 = y0 + 1;
    float wy0 = (y0 >= 0 && y0 < DIM) ? (1.0f - fy) : 0.0f;
    float wy1 = (y1 >= 0 && y1 < DIM) ? fy : 0.0f;
    int yc0 = min(max(y0, 0), DIM - 1), yc1 = min(max(y1, 0), DIM - 1);

    float w00 = wz0 * wy0, w01 = wz0 * wy1, w10 = wz1 * wy0, w11 = wz1 * wy1;

    // per-m x-axis weights (validity folded in)
    float wx0[4], wx1[4];
#pragma unroll
    for (int m = 0; m < 4; ++m) {
        int c0 = k + m + iox, c1 = c0 + 1;
        wx0[m] = (c0 >= 0 && c0 < DIM) ? (1.0f - fx) : 0.0f;
        wx1[m] = (c1 >= 0 && c1 < DIM) ? fx : 0.0f;
    }

    // aligned 8-float span per row: columns [cb, cb+7] cover [k+iox, k+iox+4]
    int a  = iox & 3;                 // wave-uniform
    int cb = k + (iox - a);           // multiple of 4

    long long base = (long long)b * (DIM * DIM * DIM);
    long long o00 = base + ((long long)zc0 * DIM + yc0) * DIM;
    long long o01 = base + ((long long)zc0 * DIM + yc1) * DIM;
    long long o10 = base + ((long long)zc1 * DIM + yc0) * DIM;
    long long o11 = base + ((long long)zc1 * DIM + yc1) * DIM;

    long long q00 = o00 + cb, q01 = o01 + cb, q10 = o10 + cb, q11 = o11 + cb;
    const long long HI = (long long)NVOX - 8;
    long long c00 = q00 < 0 ? 0 : (q00 > HI ? HI : q00);
    long long c01 = q01 < 0 ? 0 : (q01 > HI ? HI : q01);
    long long c10 = q10 < 0 ? 0 : (q10 > HI ? HI : q10);
    long long c11 = q11 < 0 ? 0 : (q11 > HI ? HI : q11);
    bool bad = (c00 != q00) | (c01 != q01) | (c10 != q10) | (c11 != q11);

    float f00[8], f01[8], f10[8], f11[8];
    *reinterpret_cast<float4*>(&f00[0]) = *reinterpret_cast<const float4*>(x + c00);
    *reinterpret_cast<float4*>(&f00[4]) = *reinterpret_cast<const float4*>(x + c00 + 4);
    *reinterpret_cast<float4*>(&f01[0]) = *reinterpret_cast<const float4*>(x + c01);
    *reinterpret_cast<float4*>(&f01[4]) = *reinterpret_cast<const float4*>(x + c01 + 4);
    *reinterpret_cast<float4*>(&f10[0]) = *reinterpret_cast<const float4*>(x + c10);
    *reinterpret_cast<float4*>(&f10[4]) = *reinterpret_cast<const float4*>(x + c10 + 4);
    *reinterpret_cast<float4*>(&f11[0]) = *reinterpret_cast<const float4*>(x + c11);
    *reinterpret_cast<float4*>(&f11[4]) = *reinterpret_cast<const float4*>(x + c11 + 4);

    float res[4];
#define DOCASE(A)                                                          \
    _Pragma("unroll")                                                      \
    for (int m = 0; m < 4; ++m) {                                          \
        float v00 = wx0[m] * f00[A + m] + wx1[m] * f00[A + m + 1];         \
        float v01 = wx0[m] * f01[A + m] + wx1[m] * f01[A + m + 1];         \
        float v10 = wx0[m] * f10[A + m] + wx1[m] * f10[A + m + 1];         \
        float v11 = wx0[m] * f11[A + m] + wx1[m] * f11[A + m + 1];         \
        res[m] = w00 * v00 + w01 * v01 + w10 * v10 + w11 * v11;            \
    }
    switch (a) {                      // uniform branch, indices compile-time
        case 0: DOCASE(0); break;
        case 1: DOCASE(1); break;
        case 2: DOCASE(2); break;
        default: DOCASE(3); break;
    }
#undef DOCASE

    if (bad) {                        // rare buffer-edge lanes: exact scalar path
        const float* xb  = x + base;
        const float* r00 = xb + (zc0 * DIM + yc0) * DIM;
        const float* r01 = xb + (zc0 * DIM + yc1) * DIM;
        const float* r10 = xb + (zc1 * DIM + yc0) * DIM;
        const float* r11 = xb + (zc1 * DIM + yc1) * DIM;
#pragma unroll
        for (int m = 0; m < 4; ++m) {
            int c0 = k + m + iox, c1 = c0 + 1;
            int cc0 = min(max(c0, 0), DIM - 1), cc1 = min(max(c1, 0), DIM - 1);
            float v00 = wx0[m] * r00[cc0] + wx1[m] * r00[cc1];
            float v01 = wx0[m] * r01[cc0] + wx1[m] * r01[cc1];
            float v10 = wx0[m] * r10[cc0] + wx1[m] * r10[cc1];
            float v11 = wx0[m] * r11[cc0] + wx1[m] * r11[cc1];
            res[m] = w00 * v00 + w01 * v01 + w10 * v10 + w11 * v11;
        }
    }

    reinterpret_cast<float4*>(out)[t] =
        make_float4(res[0], res[1], res[2], res[3]);

    const float step = 2.0f / 191.0f;
    float gj = fmaf((float)j, step, -1.0f) + tyf;
    float gi = fmaf((float)i, step, -1.0f) + tzf;
    float g0 = fmaf((float)(k + 0), step, -1.0f) + txf;
    float g1 = fmaf((float)(k + 1), step, -1.0f) + txf;
    float g2 = fmaf((float)(k + 2), step, -1.0f) + txf;
    float g3 = fmaf((float)(k + 3), step, -1.0f) + txf;

    float* g = out + TSIZE + (size_t)idx * 3;
    reinterpret_cast<float4*>(g)[0] = make_float4(g0, gj, gi, g1);
    reinterpret_cast<float4*>(g)[1] = make_float4(gj, gi, g2, gj);
    reinterpret_cast<float4*>(g)[2] = make_float4(gi, g3, gj, gi);
}

extern "C" void kernel_launch(void* const* d_in, const int* in_sizes, int n_in,
                              void* d_out, int out_size, void* d_ws, size_t ws_size,
                              hipStream_t stream) {
    const float* x = (const float*)d_in[0];
    const float* y = (const float*)d_in[1];
    float* out = (float*)d_out;
    double* ws = (double*)d_ws;

    hipMemsetAsync(ws, 0, 8 * sizeof(double), stream);
    com_reduce<<<2048, 256, 0, stream>>>(x, y, ws);
    com_finalize<<<1, 64, 0, stream>>>(ws);
    com_apply<<<N4 / 256, 256, 0, stream>>>(x, out, ws);
}

// Round 3
// 92.505 us; speedup vs baseline: 1.7601x; 1.2461x over previous
//
#include <hip/hip_runtime.h>

static constexpr int DIM    = 192;
static constexpr int NVOX   = 2 * DIM * DIM * DIM;   // 14,155,776
static constexpr int N4     = NVOX / 4;              // 3,538,944
static constexpr int TSIZE  = NVOX;
static constexpr int RBLOCKS = 2048;
// ws layout (floats): [0..5] fx,fy,fz,tx,ty,tz ; [6..8] iox,ioy,ioz (int)
// [16 .. 16+RBLOCKS*8) per-block partials (float)

// ---------------- Kernel 1: per-block partial reductions (no atomics) ----------------
__global__ __launch_bounds__(256) void com_reduce(const float* __restrict__ x,
                                                  const float* __restrict__ y,
                                                  float* __restrict__ ws) {
    const float step = 2.0f / 191.0f;
    float a0 = 0, a1 = 0, a2 = 0, a3 = 0;
    float b0 = 0, b1 = 0, b2 = 0, b3 = 0;

    for (int t = blockIdx.x * blockDim.x + threadIdx.x; t < N4;
         t += gridDim.x * blockDim.x) {
        int idx = t * 4;
        int k = idx % DIM;
        int r = idx / DIM;
        int j = r % DIM;
        int i = (r / DIM) % DIM;

        float4 xv = reinterpret_cast<const float4*>(x)[t];
        float4 yv = reinterpret_cast<const float4*>(y)[t];

        float gj = fmaf((float)j, step, -1.0f);
        float gi = fmaf((float)i, step, -1.0f);
        float g0 = fmaf((float)(k + 0), step, -1.0f);
        float g1 = fmaf((float)(k + 1), step, -1.0f);
        float g2 = fmaf((float)(k + 2), step, -1.0f);
        float g3 = fmaf((float)(k + 3), step, -1.0f);

        float xs  = (xv.x + xv.y) + (xv.z + xv.w);
        float ys  = (yv.x + yv.y) + (yv.z + yv.w);
        float xgx = xv.x * g0 + xv.y * g1 + xv.z * g2 + xv.w * g3;
        float ygx = yv.x * g0 + yv.y * g1 + yv.z * g2 + yv.w * g3;

        a0 += xs;  a1 += xgx;  a2 += xs * gj;  a3 += xs * gi;
        b0 += ys;  b1 += ygx;  b2 += ys * gj;  b3 += ys * gi;
    }

    float v[8] = {a0, a1, a2, a3, b0, b1, b2, b3};
#pragma unroll
    for (int q = 0; q < 8; ++q) {
#pragma unroll
        for (int off = 32; off > 0; off >>= 1)
            v[q] += __shfl_down(v[q], off, 64);
    }

    __shared__ float sm[4][8];
    int lane = threadIdx.x & 63;
    int wave = threadIdx.x >> 6;
    if (lane == 0) {
#pragma unroll
        for (int q = 0; q < 8; ++q) sm[wave][q] = v[q];
    }
    __syncthreads();
    if (threadIdx.x < 8) {
        float s = sm[0][threadIdx.x] + sm[1][threadIdx.x] +
                  sm[2][threadIdx.x] + sm[3][threadIdx.x];
        ws[16 + blockIdx.x * 8 + threadIdx.x] = s;
    }
}

// ---------------- Kernel 1.5: fold partials into sampling params ----------------
__global__ __launch_bounds__(256) void com_finalize(float* __restrict__ ws) {
    __shared__ double sd[256];
    int t = threadIdx.x;
    int q = t & 7;
    double s = 0;
    for (int p = t >> 3; p < RBLOCKS; p += 32)
        s += (double)ws[16 + p * 8 + q];
    sd[t] = s;
    __syncthreads();
    for (int off = 128; off >= 8; off >>= 1) {
        if (t < off) sd[t] += sd[t + off];
        __syncthreads();
    }
    if (t == 0) {
        double xs = sd[0], xgx = sd[1], xgy = sd[2], xgz = sd[3];
        double ys = sd[4], ygx = sd[5], ygy = sd[6], ygz = sd[7];
        double tx = xgx / xs - ygx / ys;
        double ty = xgy / xs - ygy / ys;
        double tz = xgz / xs - ygz / ys;
        double sx = tx * 95.5, sy = ty * 95.5, sz = tz * 95.5;
        double fsx = floor(sx), fsy = floor(sy), fsz = floor(sz);
        ws[0] = (float)(sx - fsx);
        ws[1] = (float)(sy - fsy);
        ws[2] = (float)(sz - fsz);
        ws[3] = (float)tx;
        ws[4] = (float)ty;
        ws[5] = (float)tz;
        int* ip = reinterpret_cast<int*>(ws + 6);
        ip[0] = (int)fsx; ip[1] = (int)fsy; ip[2] = (int)fsz;
    }
}

// ---------------- Kernel 2: LDS-staged constant-shift trilinear + grid write ----------------
// block = (b, i, 4 consecutive j). 192 threads. 5 z-combined y-rows staged in LDS.
__global__ __launch_bounds__(192) void com_apply(const float* __restrict__ x,
                                                 float* __restrict__ out,
                                                 const float* __restrict__ ws) {
    float fx = ws[0], fy = ws[1], fz = ws[2];
    float txf = ws[3], tyf = ws[4], tzf = ws[5];
    const int* ip = reinterpret_cast<const int*>(ws + 6);
    int iox = ip[0], ioy = ip[1], ioz = ip[2];

    int bid = blockIdx.x;
    int jg = bid % 48;
    int i  = (bid / 48) % DIM;
    int b  = bid / (48 * DIM);
    int j0 = jg * 4;
    int tid = threadIdx.x;

    int z0 = i + ioz, z1 = z0 + 1;
    float wz0 = (z0 >= 0 && z0 < DIM) ? 1.0f - fz : 0.0f;
    float wz1 = (z1 >= 0 && z1 < DIM) ? fz : 0.0f;
    int zc0 = min(max(z0, 0), DIM - 1), zc1 = min(max(z1, 0), DIM - 1);

    __shared__ float srow[5][240];   // data at cols [16, 208); pads zeroed

    // zero the padding (cols 0..15 and 208..239 of each row)
    for (int p = tid; p < 240; p += 192) {
        int m = p / 48, cc = p % 48;
        int col = (cc < 16) ? cc : (cc - 16 + 208);
        srow[m][col] = 0.0f;
    }

    const float* xb = x + (size_t)b * (DIM * DIM * DIM);
#pragma unroll 2
    for (int task = tid; task < 240; task += 192) {
        int m = task / 48;
        int c = (task % 48) * 4;
        int yv = j0 + ioy + m;
        int yc = min(max(yv, 0), DIM - 1);
        const float* p0 = xb + (zc0 * DIM + yc) * DIM + c;
        const float* p1 = xb + (zc1 * DIM + yc) * DIM + c;
        float4 va = *reinterpret_cast<const float4*>(p0);
        float4 vb = *reinterpret_cast<const float4*>(p1);
        float4 s;
        s.x = wz0 * va.x + wz1 * vb.x;
        s.y = wz0 * va.y + wz1 * vb.y;
        s.z = wz0 * va.z + wz1 * vb.z;
        s.w = wz0 * va.w + wz1 * vb.w;
        *reinterpret_cast<float4*>(&srow[m][16 + c]) = s;
    }
    __syncthreads();

    int rr = tid / 48;
    int k4 = tid % 48;
    int k  = k4 * 4;
    int j  = j0 + rr;
    int yv0 = j + ioy, yv1 = yv0 + 1;
    float wy0 = (yv0 >= 0 && yv0 < DIM) ? 1.0f - fy : 0.0f;
    float wy1 = (yv1 >= 0 && yv1 < DIM) ? fy : 0.0f;

    float wx0[4], wx1[4];
#pragma unroll
    for (int m = 0; m < 4; ++m) {
        int c0 = k + m + iox, c1 = c0 + 1;
        wx0[m] = (c0 >= 0 && c0 < DIM) ? 1.0f - fx : 0.0f;
        wx1[m] = (c1 >= 0 && c1 < DIM) ? fx : 0.0f;
    }

    int a  = iox & 3;                 // wave-uniform
    int cb = 16 + k + (iox - a);      // 16B-aligned LDS float index
    float f0[8], f1[8];
    *reinterpret_cast<float4*>(&f0[0]) = *reinterpret_cast<const float4*>(&srow[rr][cb]);
    *reinterpret_cast<float4*>(&f0[4]) = *reinterpret_cast<const float4*>(&srow[rr][cb + 4]);
    *reinterpret_cast<float4*>(&f1[0]) = *reinterpret_cast<const float4*>(&srow[rr + 1][cb]);
    *reinterpret_cast<float4*>(&f1[4]) = *reinterpret_cast<const float4*>(&srow[rr + 1][cb + 4]);

    float res[4];
#define DOCASE(A)                                                           \
    _Pragma("unroll")                                                       \
    for (int m = 0; m < 4; ++m) {                                           \
        float u0 = wy0 * f0[A + m]     + wy1 * f1[A + m];                   \
        float u1 = wy0 * f0[A + m + 1] + wy1 * f1[A + m + 1];               \
        res[m] = wx0[m] * u0 + wx1[m] * u1;                                 \
    }
    switch (a) {
        case 0: DOCASE(0); break;
        case 1: DOCASE(1); break;
        case 2: DOCASE(2); break;
        default: DOCASE(3); break;
    }
#undef DOCASE

    reinterpret_cast<float4*>(out)[bid * 192 + tid] =
        make_float4(res[0], res[1], res[2], res[3]);

    // grid output: block region = floats [TSIZE + bid*2304, +2304), written
    // lane-contiguously; every element is a pure function of its index.
    const float step = 2.0f / 191.0f;
    float gzv = fmaf((float)i, step, -1.0f) + tzf;   // comp 2, block-constant
    int g4base = TSIZE / 4 + bid * 576;
#pragma unroll
    for (int s = 0; s < 3; ++s) {
        float4 gv;
#pragma unroll
        for (int u = 0; u < 4; ++u) {
            int L = (tid + s * 192) * 4 + u;   // local float index in region
            int lv = L / 3;                    // local voxel 0..767
            int comp = L - lv * 3;
            int kk = lv % DIM;
            int rj = lv / DIM;                 // 0..3
            float val;
            if (comp == 0)      val = fmaf((float)kk, step, -1.0f) + txf;
            else if (comp == 1) val = fmaf((float)(j0 + rj), step, -1.0f) + tyf;
            else                val = gzv;
            reinterpret_cast<float*>(&gv)[u] = val;
        }
        reinterpret_cast<float4*>(out)[g4base + tid + s * 192] = gv;
    }
}

extern "C" void kernel_launch(void* const* d_in, const int* in_sizes, int n_in,
                              void* d_out, int out_size, void* d_ws, size_t ws_size,
                              hipStream_t stream) {
    const float* x = (const float*)d_in[0];
    const float* y = (const float*)d_in[1];
    float* out = (float*)d_out;
    float* ws = (float*)d_ws;

    com_reduce<<<RBLOCKS, 256, 0, stream>>>(x, y, ws);
    com_finalize<<<1, 256, 0, stream>>>(ws);
    com_apply<<<NVOX / 768, 192, 0, stream>>>(x, out, ws);
}